// Round 5
// baseline (546.813 us; speedup 1.0000x reference)
//
#include <hip/hip_runtime.h>
#include <stdint.h>
#include <stddef.h>

// GAT layer, N=8192, Fin=512, F=256 on gfx950.
// R5: adj (256MB int32) compressed once by k_mask into an 8MB bitmask laid
// out so each k_attn lane loads its mask for 16 phases as ONE 16B register
// load (zero per-phase adj latency/BW). k_attn rebuilt: 64x256 blocks,
// launch_bounds(512,4) -> 128 VGPR (R4's 32-VGPR serialization fixed),
// mask in regs + s2 in LDS + coalesced B from HTf + bank-clean P LDS.

#define N_NODES 8192
#define FIN     512
#define FOUT    256
#define LRALPHA 0.2f
#define MI_SHIFT 16.0f   // >= max s2 (sigma~1.3); exact-math upper bound

typedef float f32x4 __attribute__((ext_vector_type(4)));
typedef short s16x8 __attribute__((ext_vector_type(8)));
typedef unsigned short u16x4 __attribute__((ext_vector_type(4)));
typedef int   i32x4 __attribute__((ext_vector_type(4)));
typedef unsigned long long u64;

__device__ __forceinline__ short f2bf_rne(float f) {
  uint32_t u = __builtin_bit_cast(uint32_t, f);
  u += 0x7fffu + ((u >> 16) & 1u);
  return (short)(u >> 16);
}
__device__ __forceinline__ short f2bf_fast(float f) {   // round-half-up
  uint32_t u = __builtin_bit_cast(uint32_t, f);
  return (short)((u + 0x8000u) >> 16);
}
__device__ __forceinline__ float bf2f(short s) {
  uint32_t u = ((uint32_t)(uint16_t)s) << 16;
  return __builtin_bit_cast(float, u);
}

// ---------------------------------------------------------------------------
// K_mask: M3 bitmask of adj. Layout: byte index = row*1024 + c*64 + jp,
// bit e of that byte = (adj[row][jp*128 + c*8 + e] != 0),  c=0..15, jp=0..63.
// One block per row; wave w covers jp in [16w,16w+16) (j in [2048w, +2048)).
// Per 256-int group: 4 coalesced dword loads + 4 ballots (bit L = lane L ->
// j = 2048w + 256gg + 64t + L); lane (c=L>>2, J=L&3) assembles u32 of bytes
// jp = 16w+4J..+4, writes coalesced-ish (16 segs of 16B per wave).
// ---------------------------------------------------------------------------
__global__ __launch_bounds__(256) void k_mask(const int* __restrict__ adj,
                                              uint32_t* __restrict__ M3) {
  const int row = blockIdx.x;
  const int w   = threadIdx.x >> 6;
  const int L   = threadIdx.x & 63;
  const int c   = L >> 2;
  const int J   = L & 3;
  const int ch  = c >> 3;      // ballot t-parity for this lane's c
  const int cb  = (c & 7) * 8; // bit shift of this lane's byte within ballot
  const int* base = adj + (size_t)row * N_NODES + w * 2048;
  uint32_t accum = 0;
#pragma unroll
  for (int gg = 0; gg < 8; ++gg) {
    int v0 = base[gg * 256 + L];
    int v1 = base[gg * 256 + 64 + L];
    int v2 = base[gg * 256 + 128 + L];
    int v3 = base[gg * 256 + 192 + L];
    u64 b0 = __ballot(v0 != 0);
    u64 b1 = __ballot(v1 != 0);
    u64 b2 = __ballot(v2 != 0);
    u64 b3 = __ballot(v3 != 0);
#pragma unroll
    for (int th = 0; th < 2; ++th) {
      // t = th*2 + ch; jp_local = 2*gg + th; my u32 covers jp_local J*4..J*4+3
      u64 bsel = ch ? (th ? b3 : b1) : (th ? b2 : b0);
      int slot = 2 * gg + th - J * 4;
      uint32_t byte = (uint32_t)(bsel >> cb) & 0xffu;
      accum |= (slot >= 0 && slot < 4) ? (byte << (8 * (slot & 3))) : 0u;
    }
  }
  M3[(size_t)row * 256 + c * 16 + w * 4 + J] = accum;
}

// ---------------------------------------------------------------------------
// K0: WThi/WTlo[256][512] bf16 hi/lo split of W (transposed).
// ---------------------------------------------------------------------------
__global__ __launch_bounds__(256) void k_prep(const float* __restrict__ W,
                                              uint16_t* __restrict__ WThi,
                                              uint16_t* __restrict__ WTlo) {
  const int idx = blockIdx.x * 256 + threadIdx.x;
  const int n = idx >> 9;
  const int k = idx & 511;
  float v = W[k * FOUT + n];
  short h = f2bf_rne(v);
  WThi[idx] = (uint16_t)h;
  WTlo[idx] = (uint16_t)f2bf_rne(v - bf2f(h));
}

// ---------------------------------------------------------------------------
// K1: fused H = X@W (bf16 hi/lo, 3 MFMAs) + s1/s2 rowdots + HTf store.
// HTf layout (B-frag linear): HTf[jt=j/32][c16=col/16][lane=(q<<4)|m][e]
//   = H[j = jt*32 + q*8 + e][col = c16*16 + m].
// ---------------------------------------------------------------------------
__global__ __launch_bounds__(256) void k_gemm_fused(const float* __restrict__ X,
                                                    const uint16_t* __restrict__ WThi,
                                                    const uint16_t* __restrict__ WTlo,
                                                    const float* __restrict__ a,
                                                    uint16_t* __restrict__ HTf,
                                                    float* __restrict__ s1g,
                                                    float* __restrict__ s2g) {
  __shared__ float ls1[16], ls2[16];
  __shared__ uint16_t tile[FOUT * 16];   // [col][row_local]
  const int lane = threadIdx.x & 63;
  const int w    = threadIdx.x >> 6;
  const int m    = lane & 15;
  const int quad = lane >> 4;
  const int i0   = blockIdx.x * 16;
  const int colg = w * 64;

  f32x4 acc[4];
#pragma unroll
  for (int cb = 0; cb < 4; ++cb) { f32x4 z = {0.f,0.f,0.f,0.f}; acc[cb] = z; }

  for (int kt = 0; kt < FIN / 32; ++kt) {
    const int k0 = kt * 32 + quad * 8;
    const float* ap = X + (size_t)(i0 + m) * FIN + k0;
    f32x4 a0 = *(const f32x4*)ap;
    f32x4 a1 = *(const f32x4*)(ap + 4);
    s16x8 ahi, alo;
#pragma unroll
    for (int e = 0; e < 4; ++e) {
      short h0 = f2bf_rne(a0[e]); ahi[e] = h0; alo[e] = f2bf_rne(a0[e] - bf2f(h0));
      short h1 = f2bf_rne(a1[e]); ahi[4+e] = h1; alo[4+e] = f2bf_rne(a1[e] - bf2f(h1));
    }
#pragma unroll
    for (int cb = 0; cb < 4; ++cb) {
      const int n = colg + cb * 16 + m;
      s16x8 bhi = *(const s16x8*)(WThi + (size_t)n * FIN + k0);
      s16x8 blo = *(const s16x8*)(WTlo + (size_t)n * FIN + k0);
      acc[cb] = __builtin_amdgcn_mfma_f32_16x16x32_bf16(ahi, bhi, acc[cb], 0, 0, 0);
      acc[cb] = __builtin_amdgcn_mfma_f32_16x16x32_bf16(ahi, blo, acc[cb], 0, 0, 0);
      acc[cb] = __builtin_amdgcn_mfma_f32_16x16x32_bf16(alo, bhi, acc[cb], 0, 0, 0);
    }
  }

  float p1[4] = {0.f,0.f,0.f,0.f}, p2[4] = {0.f,0.f,0.f,0.f};
#pragma unroll
  for (int cb = 0; cb < 4; ++cb) {
    const int n = colg + cb * 16 + m;
    const float a1c = a[n];
    const float a2c = a[FOUT + n];
#pragma unroll
    for (int reg = 0; reg < 4; ++reg) {
      p1[reg] += acc[cb][reg] * a1c;
      p2[reg] += acc[cb][reg] * a2c;
    }
  }
#pragma unroll
  for (int off = 1; off <= 8; off <<= 1)
#pragma unroll
    for (int reg = 0; reg < 4; ++reg) {
      p1[reg] += __shfl_xor(p1[reg], off);
      p2[reg] += __shfl_xor(p2[reg], off);
    }
  if (threadIdx.x < 16) { ls1[threadIdx.x] = 0.f; ls2[threadIdx.x] = 0.f; }
  __syncthreads();
  if (m == 0) {
#pragma unroll
    for (int reg = 0; reg < 4; ++reg) {
      atomicAdd(&ls1[quad * 4 + reg], p1[reg]);
      atomicAdd(&ls2[quad * 4 + reg], p2[reg]);
    }
  }
#pragma unroll
  for (int cb = 0; cb < 4; ++cb) {
    const int col = colg + cb * 16 + m;
    u16x4 pk;
#pragma unroll
    for (int reg = 0; reg < 4; ++reg) pk[reg] = (uint16_t)f2bf_rne(acc[cb][reg]);
    *(u16x4*)(tile + col * 16 + quad * 4) = pk;
  }
  __syncthreads();
  const int t = threadIdx.x;
  if (t < 16) { s1g[i0 + t] = ls1[t]; s2g[i0 + t] = ls2[t]; }
  const int jt = i0 >> 5;
  const int qh = (i0 >> 4) & 1;
  const int c  = t >> 4;
  const int mm = t & 15;
#pragma unroll
  for (int qq = 0; qq < 2; ++qq) {
    uint4 v = *(const uint4*)(tile + (c * 16 + mm) * 16 + qq * 8);
    *(uint4*)(HTf + ((((size_t)jt * 16 + c) * 64) + (qh * 2 + qq) * 16 + mm) * 8) = v;
  }
}

// ---------------------------------------------------------------------------
// K2: fused masked-softmax attention + P@H partial.
// grid = (128, split). Block: 64 rows x 256 cols, j-slice [jbeg,+jrange).
// 8 waves: wave w = (rg=w>>2: 32-row group) x (cg=w&3: 64-col group).
// Phase = 128 j. Producer: lane (rl=lane&31 [+32], cpr=2w+(lane>>5)) computes
// 16 exps -> P rows rl, rl+32 for j-window cpr*8..+8; mask bits from regs
// (16B load per 16 phases); s2 from LDS. P in LDS [c][rl64][e] dbuf
// (write 4-way banks, read 2-way=free), 1 barrier/phase. Consumer: 4 js x
// (2rt x 4cb) = 32 MFMAs; B coalesced b128 from HTf (L2-hot).
// ---------------------------------------------------------------------------
__global__ __launch_bounds__(512, 4) void k_attn(const uint32_t* __restrict__ M3,
                                                 const uint16_t* __restrict__ HTf,
                                                 const float* __restrict__ s1,
                                                 const float* __restrict__ s2,
                                                 float* __restrict__ pout,
                                                 float* __restrict__ pden,
                                                 int split) {
  __shared__ uint16_t PL[2][8192];   // [c 16][rl 64][e 8]
  __shared__ float lss2[2048];
  __shared__ float ldsden[512];

  const int tid  = threadIdx.x;
  const int lane = tid & 63;
  const int w    = tid >> 6;
  const int m    = lane & 15;
  const int q    = lane >> 4;
  const int rl   = lane & 31;
  const int cpr  = w * 2 + (lane >> 5);
  const int cg   = w & 3, rg = w >> 2;
  const int i0   = blockIdx.x * 64;
  const int sp   = blockIdx.y;
  const int jrange = N_NODES / split;
  const int jbeg   = sp * jrange;
  const int npb    = jrange / 2048;   // 16-phase super-blocks

  const float s1r0 = s1[i0 + rl];
  const float s1r1 = s1[i0 + 32 + rl];
  float mi0 = fmaxf(s1r0 + MI_SHIFT, LRALPHA * (s1r0 + MI_SHIFT));
  float mi1 = fmaxf(s1r1 + MI_SHIFT, LRALPHA * (s1r1 + MI_SHIFT));

  f32x4 acc[2][4];
#pragma unroll
  for (int rt = 0; rt < 2; ++rt)
#pragma unroll
    for (int cb = 0; cb < 4; ++cb) { f32x4 z = {0.f,0.f,0.f,0.f}; acc[rt][cb] = z; }
  float den0 = 0.f, den1 = 0.f;

  const uint8_t* mrow0 = (const uint8_t*)M3 + ((size_t)(i0 + rl) << 10) + cpr * 64 + (jbeg >> 7);
  const uint8_t* mrow1 = mrow0 + (32u << 10);
  const int pwoff = (cpr * 64 + rl) * 8;
  const uint16_t* hB = HTf + ((size_t)(jbeg >> 5) * 16 + cg * 4) * 512 + lane * 8;

#pragma unroll 1
  for (int pb = 0; pb < npb; ++pb) {
    // stage this super-block's s2 (2048 j) and mask (16 phases in 16B)
    f32x4 sstage = *(const f32x4*)(s2 + jbeg + pb * 2048 + tid * 4);
    uint4 mk0 = *(const uint4*)(mrow0 + pb * 16);
    uint4 mk1 = *(const uint4*)(mrow1 + pb * 16);
    const u64 m0lo = mk0.x | ((u64)mk0.y << 32), m0hi = mk0.z | ((u64)mk0.w << 32);
    const u64 m1lo = mk1.x | ((u64)mk1.y << 32), m1hi = mk1.z | ((u64)mk1.w << 32);
    *(f32x4*)(lss2 + tid * 4) = sstage;
    __syncthreads();   // lss2 ready (prev phases all consumed: see barrier proof)

#pragma unroll 1
    for (int pp = 0; pp < 16; ++pp) {
      // B-frags: first half (js 0,1) issued before the exp block
      s16x8 B[4][4];
      const uint16_t* hp = hB + (size_t)((pb * 16 + pp) * 4) * (16 * 512);
#pragma unroll
      for (int js = 0; js < 2; ++js)
#pragma unroll
        for (int cb = 0; cb < 4; ++cb)
          B[js][cb] = *(const s16x8*)(hp + (size_t)js * (16 * 512) + cb * 512);
      // mask bytes for this phase (registers only)
      const u64 sel0 = (pp & 8) ? m0hi : m0lo;
      const u64 sel1 = (pp & 8) ? m1hi : m1lo;
      const uint32_t by0 = (uint32_t)(sel0 >> ((pp & 7) * 8)) & 0xffu;
      const uint32_t by1 = (uint32_t)(sel1 >> ((pp & 7) * 8)) & 0xffu;
      // P-gen: 16 exps (rows rl, rl+32; j-window cpr*8..+8)
      f32x4 sA = *(const f32x4*)(lss2 + pp * 128 + cpr * 8);
      f32x4 sB = *(const f32x4*)(lss2 + pp * 128 + cpr * 8 + 4);
      s16x8 P0, P1;
#pragma unroll
      for (int e = 0; e < 4; ++e) {
        float x0 = s1r0 + sA[e];
        float p0 = __expf(fmaxf(x0, LRALPHA * x0) - mi0);
        p0 = ((by0 >> e) & 1u) ? p0 : 0.f;
        den0 += p0; P0[e] = f2bf_fast(p0);
        float x1 = s1r0 + sB[e];
        float p1v = __expf(fmaxf(x1, LRALPHA * x1) - mi0);
        p1v = ((by0 >> (e + 4)) & 1u) ? p1v : 0.f;
        den0 += p1v; P0[4 + e] = f2bf_fast(p1v);
        float x2 = s1r1 + sA[e];
        float p2v = __expf(fmaxf(x2, LRALPHA * x2) - mi1);
        p2v = ((by1 >> e) & 1u) ? p2v : 0.f;
        den1 += p2v; P1[e] = f2bf_fast(p2v);
        float x3 = s1r1 + sB[e];
        float p3v = __expf(fmaxf(x3, LRALPHA * x3) - mi1);
        p3v = ((by1 >> (e + 4)) & 1u) ? p3v : 0.f;
        den1 += p3v; P1[4 + e] = f2bf_fast(p3v);
      }
      uint16_t* Pw = PL[pp & 1];
      *(s16x8*)(Pw + pwoff) = P0;
      *(s16x8*)(Pw + pwoff + 32 * 8) = P1;
      // B-frags: second half (js 2,3) before the barrier drain
#pragma unroll
      for (int js = 2; js < 4; ++js)
#pragma unroll
        for (int cb = 0; cb < 4; ++cb)
          B[js][cb] = *(const s16x8*)(hp + (size_t)js * (16 * 512) + cb * 512);
      __syncthreads();   // P-tile complete (dbuf guards next write)
      // consume: 4 js x (2 rt x 4 cb) MFMAs
#pragma unroll
      for (int js = 0; js < 4; ++js) {
        const uint16_t* pc = Pw + ((js * 4 + q) * 64 + rg * 32 + m) * 8;
        s16x8 f0 = *(const s16x8*)pc;
        s16x8 f1 = *(const s16x8*)(pc + 16 * 8);
#pragma unroll
        for (int cb = 0; cb < 4; ++cb) {
          acc[0][cb] = __builtin_amdgcn_mfma_f32_16x16x32_bf16(f0, B[js][cb], acc[0][cb], 0, 0, 0);
          acc[1][cb] = __builtin_amdgcn_mfma_f32_16x16x32_bf16(f1, B[js][cb], acc[1][cb], 0, 0, 0);
        }
      }
    }
  }

  // denominators: lane^32 merges this wave's two c-windows, LDS merges waves
  den0 += __shfl_xor(den0, 32);
  den1 += __shfl_xor(den1, 32);
  if (lane < 32) {
    ldsden[w * 64 + rl] = den0;
    ldsden[w * 64 + 32 + rl] = den1;
  }
  __syncthreads();
  if (tid < 64) {
    float d = 0.f;
#pragma unroll
    for (int wv = 0; wv < 8; ++wv) d += ldsden[wv * 64 + tid];
    pden[(size_t)sp * N_NODES + i0 + tid] = d;
  }
#pragma unroll
  for (int rt = 0; rt < 2; ++rt)
#pragma unroll
    for (int cb = 0; cb < 4; ++cb)
#pragma unroll
      for (int reg = 0; reg < 4; ++reg) {
        const int row = i0 + rg * 32 + rt * 16 + q * 4 + reg;
        const int col = cg * 64 + cb * 16 + m;
        pout[((size_t)sp * N_NODES + row) * FOUT + col] = acc[rt][cb][reg];
      }
}

// ---------------------------------------------------------------------------
// K3: out = elu( (sum_s pout[s]) / (sum_s pden[s]) ). In-place safe (split=1).
// ---------------------------------------------------------------------------
__global__ __launch_bounds__(256) void k_reduce(const float* __restrict__ pout,
                                                const float* __restrict__ pden,
                                                float* __restrict__ out,
                                                int split) {
  const int gid = blockIdx.x * 256 + threadIdx.x;
  const int i = gid >> 6;
  const int c = (gid & 63) << 2;
  f32x4 sum = {0.f,0.f,0.f,0.f};
  float den = 0.f;
  for (int s = 0; s < split; ++s) {
    sum += *(const f32x4*)(pout + ((size_t)s * N_NODES + i) * FOUT + c);
    den += pden[(size_t)s * N_NODES + i];
  }
  const float inv = 1.0f / den;
  f32x4 r;
#pragma unroll
  for (int e = 0; e < 4; ++e) {
    float v = sum[e] * inv;
    r[e] = v > 0.f ? v : (__expf(v) - 1.0f);
  }
  *(f32x4*)(out + (size_t)i * FOUT + c) = r;
}

// ---------------------------------------------------------------------------
extern "C" void kernel_launch(void* const* d_in, const int* in_sizes, int n_in,
                              void* d_out, int out_size, void* d_ws, size_t ws_size,
                              hipStream_t stream) {
  const float* X   = (const float*)d_in[0];   // [8192][512]
  const int*   adj = (const int*)d_in[1];     // [8192][8192]
  const float* W   = (const float*)d_in[2];   // [512][256]
  const float* a   = (const float*)d_in[3];   // [512]
  float* out = (float*)d_out;                 // [8192][256]

  char* ws = (char*)d_ws;
  uint16_t* HTf  = (uint16_t*)ws;                                   // 4 MB
  uint16_t* WThi = (uint16_t*)(ws + (4u << 20));                    // 256 KB
  uint16_t* WTlo = (uint16_t*)(ws + (4u << 20) + 262144);           // 256 KB
  float*    s1   = (float*)(ws + (4u << 20) + 524288);              // 32 KB
  float*    s2   = s1 + N_NODES;                                    // 32 KB
  float*    pden = s2 + N_NODES;                                    // <=128 KB
  uint32_t* M3   = (uint32_t*)(ws + (6u << 20));                    // 8 MB
  const size_t pout_off = (size_t)16u << 20;
  const size_t slab = (size_t)N_NODES * FOUT * sizeof(float);       // 8 MB

  int split;
  if      (ws_size >= pout_off + 4 * slab) split = 4;
  else if (ws_size >= pout_off + 2 * slab) split = 2;
  else                                     split = 1;
  float* pout = (split == 1) ? out : (float*)(ws + pout_off);

  k_prep<<<dim3(512), dim3(256), 0, stream>>>(W, WThi, WTlo);
  k_mask<<<dim3(N_NODES), dim3(256), 0, stream>>>(adj, M3);
  k_gemm_fused<<<dim3(N_NODES / 16), dim3(256), 0, stream>>>(X, WThi, WTlo, a, HTf, s1, s2);
  k_attn<<<dim3(N_NODES / 64, split), dim3(512), 0, stream>>>(M3, HTf, s1, s2, pout, pden, split);
  k_reduce<<<dim3(N_NODES * FOUT / 4 / 256), dim3(256), 0, stream>>>(pout, pden, out, split);
}

// Round 7
// 472.980 us; speedup vs baseline: 1.1561x; 1.1561x over previous
//
#include <hip/hip_runtime.h>
#include <stdint.h>
#include <stddef.h>

// GAT layer, N=8192, Fin=512, F=256 on gfx950.
// R7 = R6 + one-line correctness fix in the mask producer: only lanes L<32
// store M3 words (R6 let lanes 32..63 store zero-initialized keeps, racing
// the next wave's rows and spilling into the next iblk -> absmax 1.5).
// R6 design: k_attn with no cross-barrier register staging (B-frags loaded
// same-phase, transient), P via LDS dbuf, 1 barrier per 32-j phase, 128x256
// blocks, acc 4x4/wave. adj -> u64 ballot mask M3[iblk][jw][row]. k_pre
// fuses gemm blocks (first) + mask blocks so MFMA hides under adj stream.

#define N_NODES 8192
#define FIN     512
#define FOUT    256
#define LRALPHA 0.2f
#define MI_SHIFT 16.0f   // >= max s2 (sigma~1.3); exact-math upper bound

typedef float f32x4 __attribute__((ext_vector_type(4)));
typedef short s16x8 __attribute__((ext_vector_type(8)));
typedef unsigned short u16x4 __attribute__((ext_vector_type(4)));
typedef int   i32x4 __attribute__((ext_vector_type(4)));
typedef unsigned long long u64;

__device__ __forceinline__ short f2bf_rne(float f) {
  uint32_t u = __builtin_bit_cast(uint32_t, f);
  u += 0x7fffu + ((u >> 16) & 1u);
  return (short)(u >> 16);
}
__device__ __forceinline__ short f2bf_fast(float f) {   // round-half-up
  uint32_t u = __builtin_bit_cast(uint32_t, f);
  return (short)((u + 0x8000u) >> 16);
}
__device__ __forceinline__ float bf2f(short s) {
  uint32_t u = ((uint32_t)(uint16_t)s) << 16;
  return __builtin_bit_cast(float, u);
}

// ---------------------------------------------------------------------------
// K0: WThi/WTlo[256][512] bf16 hi/lo split of W (transposed).
// ---------------------------------------------------------------------------
__global__ __launch_bounds__(256) void k_prep(const float* __restrict__ W,
                                              uint16_t* __restrict__ WThi,
                                              uint16_t* __restrict__ WTlo) {
  const int idx = blockIdx.x * 256 + threadIdx.x;
  const int n = idx >> 9;
  const int k = idx & 511;
  float v = W[k * FOUT + n];
  short h = f2bf_rne(v);
  WThi[idx] = (uint16_t)h;
  WTlo[idx] = (uint16_t)f2bf_rne(v - bf2f(h));
}

// ---------------------------------------------------------------------------
// K1 fused kernel: blocks [0,512) = GEMM (H=X@W + s1/s2 + HTf store),
//                  blocks [512, 2560) = adj -> ballot bitmask M3.
//
// M3 layout: u64 at [iblk=row/128][jw=j/64][r=row%128]; bit (j&63) = edge.
// Mask block bxm: iblk = bxm>>5, jc = bxm&31 -> rows iblk*128..+128,
// j in [jc*256, +256). Wave w, iter it: row = w*32+it (local), 4 coalesced
// 256B loads + 4 ballots (ballot bit L <-> j = jc*256 + quarter*64 + L).
// Lane L==it (L<32) keeps the 4 u64s; ONLY lanes L<32 store (lanes 32..63
// hold no row -> R6 bug was their zero-stores racing/corrupting).
// ---------------------------------------------------------------------------
__global__ __launch_bounds__(256, 4) void k_pre(const float* __restrict__ X,
                                                const uint16_t* __restrict__ WThi,
                                                const uint16_t* __restrict__ WTlo,
                                                const float* __restrict__ a,
                                                const int* __restrict__ adj,
                                                uint16_t* __restrict__ HTf,
                                                float* __restrict__ s1g,
                                                float* __restrict__ s2g,
                                                u64* __restrict__ M3) {
  __shared__ float ls1[16], ls2[16];
  __shared__ uint16_t tile[FOUT * 16];   // [col][row_local]
  const int lane = threadIdx.x & 63;
  const int w    = threadIdx.x >> 6;

  if (blockIdx.x >= 512) {
    // ---- mask branch ----
    const int bxm  = blockIdx.x - 512;
    const int iblk = bxm >> 5;
    const int jc   = bxm & 31;
    const int L    = lane;
    const int* base = adj + (size_t)(iblk * 128 + w * 32) * N_NODES + jc * 256 + L;
    u64 keep0 = 0, keep1 = 0, keep2 = 0, keep3 = 0;
#pragma unroll
    for (int it = 0; it < 32; ++it) {
      const int* rp = base + (size_t)it * N_NODES;
      int v0 = rp[0], v1 = rp[64], v2 = rp[128], v3 = rp[192];
      u64 b0 = __ballot(v0 != 0);
      u64 b1 = __ballot(v1 != 0);
      u64 b2 = __ballot(v2 != 0);
      u64 b3 = __ballot(v3 != 0);
      if (L == it) { keep0 = b0; keep1 = b1; keep2 = b2; keep3 = b3; }
    }
    if (L < 32) {   // R7 FIX: only the 32 row-owning lanes store
      const size_t mb = (size_t)iblk * 128 * 128 + (w * 32 + L);
      M3[mb + (size_t)(jc * 4 + 0) * 128] = keep0;
      M3[mb + (size_t)(jc * 4 + 1) * 128] = keep1;
      M3[mb + (size_t)(jc * 4 + 2) * 128] = keep2;
      M3[mb + (size_t)(jc * 4 + 3) * 128] = keep3;
    }
    return;
  }

  // ---- gemm branch ----
  const int m    = lane & 15;
  const int quad = lane >> 4;
  const int i0   = blockIdx.x * 16;
  const int colg = w * 64;

  f32x4 acc[4];
#pragma unroll
  for (int cb = 0; cb < 4; ++cb) { f32x4 z = {0.f,0.f,0.f,0.f}; acc[cb] = z; }

  for (int kt = 0; kt < FIN / 32; ++kt) {
    const int k0 = kt * 32 + quad * 8;
    const float* ap = X + (size_t)(i0 + m) * FIN + k0;
    f32x4 a0 = *(const f32x4*)ap;
    f32x4 a1 = *(const f32x4*)(ap + 4);
    s16x8 ahi, alo;
#pragma unroll
    for (int e = 0; e < 4; ++e) {
      short h0 = f2bf_rne(a0[e]); ahi[e] = h0; alo[e] = f2bf_rne(a0[e] - bf2f(h0));
      short h1 = f2bf_rne(a1[e]); ahi[4+e] = h1; alo[4+e] = f2bf_rne(a1[e] - bf2f(h1));
    }
#pragma unroll
    for (int cb = 0; cb < 4; ++cb) {
      const int n = colg + cb * 16 + m;
      s16x8 bhi = *(const s16x8*)(WThi + (size_t)n * FIN + k0);
      s16x8 blo = *(const s16x8*)(WTlo + (size_t)n * FIN + k0);
      acc[cb] = __builtin_amdgcn_mfma_f32_16x16x32_bf16(ahi, bhi, acc[cb], 0, 0, 0);
      acc[cb] = __builtin_amdgcn_mfma_f32_16x16x32_bf16(ahi, blo, acc[cb], 0, 0, 0);
      acc[cb] = __builtin_amdgcn_mfma_f32_16x16x32_bf16(alo, bhi, acc[cb], 0, 0, 0);
    }
  }

  float p1[4] = {0.f,0.f,0.f,0.f}, p2[4] = {0.f,0.f,0.f,0.f};
#pragma unroll
  for (int cb = 0; cb < 4; ++cb) {
    const int n = colg + cb * 16 + m;
    const float a1c = a[n];
    const float a2c = a[FOUT + n];
#pragma unroll
    for (int reg = 0; reg < 4; ++reg) {
      p1[reg] += acc[cb][reg] * a1c;
      p2[reg] += acc[cb][reg] * a2c;
    }
  }
#pragma unroll
  for (int off = 1; off <= 8; off <<= 1)
#pragma unroll
    for (int reg = 0; reg < 4; ++reg) {
      p1[reg] += __shfl_xor(p1[reg], off);
      p2[reg] += __shfl_xor(p2[reg], off);
    }
  if (threadIdx.x < 16) { ls1[threadIdx.x] = 0.f; ls2[threadIdx.x] = 0.f; }
  __syncthreads();
  if (m == 0) {
#pragma unroll
    for (int reg = 0; reg < 4; ++reg) {
      atomicAdd(&ls1[quad * 4 + reg], p1[reg]);
      atomicAdd(&ls2[quad * 4 + reg], p2[reg]);
    }
  }
#pragma unroll
  for (int cb = 0; cb < 4; ++cb) {
    const int col = colg + cb * 16 + m;
    u16x4 pk;
#pragma unroll
    for (int reg = 0; reg < 4; ++reg) pk[reg] = (uint16_t)f2bf_rne(acc[cb][reg]);
    *(u16x4*)(tile + col * 16 + quad * 4) = pk;
  }
  __syncthreads();
  const int t = threadIdx.x;
  if (t < 16) { s1g[i0 + t] = ls1[t]; s2g[i0 + t] = ls2[t]; }
  const int jt = i0 >> 5;
  const int qh = (i0 >> 4) & 1;
  const int c  = t >> 4;
  const int mm = t & 15;
#pragma unroll
  for (int qq = 0; qq < 2; ++qq) {
    uint4 v = *(const uint4*)(tile + (c * 16 + mm) * 16 + qq * 8);
    *(uint4*)(HTf + ((((size_t)jt * 16 + c) * 64) + (qh * 2 + qq) * 16 + mm) * 8) = v;
  }
}

// ---------------------------------------------------------------------------
// K2: fused masked-softmax attention + P@H partial.
// grid = (64, split). 512 thr = 8 waves. Block: 128 rows x 256 cols,
// j-slice [jbeg, +jrange), phase = 32 j = one K-step.
// Producer: lane (r=tid&127, cpr=tid>>7): 8 exps -> P[p&1][cpr][r][8].
// Consumer: wave (rg=w>>2, cg=w&3) owns 64x64: 4 P ds_read_b128 +
//   4 B global b128 (same-phase transient regs) + 16 MFMA. One barrier per
//   phase; P dbuf guards WAR. Mask: one u64 per lane per 2 phases.
// ---------------------------------------------------------------------------
__global__ __launch_bounds__(512, 4) void k_attn(const u64* __restrict__ M3,
                                                 const uint16_t* __restrict__ HTf,
                                                 const float* __restrict__ s1,
                                                 const float* __restrict__ s2,
                                                 float* __restrict__ pout,
                                                 float* __restrict__ pden,
                                                 int split) {
  __shared__ uint16_t PL[2][4096];   // [cpr 4][row 128][e 8] = 8 KB each
  __shared__ float lss2[1024];       // 1024-j s2 window
  __shared__ float ldsden[512];

  const int tid  = threadIdx.x;
  const int lane = tid & 63;
  const int w    = tid >> 6;
  const int m    = lane & 15;
  const int q    = lane >> 4;
  const int rg   = w >> 2, cg = w & 3;
  const int r    = tid & 127;
  const int cpr  = tid >> 7;
  const int i0   = blockIdx.x * 128;
  const int sp   = blockIdx.y;
  const int jrange = N_NODES / split;
  const int jbeg   = sp * jrange;
  const int nphase = jrange / 32;

  const float s1r = s1[i0 + r];
  float mi = fmaxf(s1r + MI_SHIFT, LRALPHA * (s1r + MI_SHIFT));

  f32x4 acc[4][4];
#pragma unroll
  for (int rt = 0; rt < 4; ++rt)
#pragma unroll
    for (int cb = 0; cb < 4; ++cb) { f32x4 z = {0.f,0.f,0.f,0.f}; acc[rt][cb] = z; }
  float den = 0.f;

  const u64* mrow = M3 + ((size_t)blockIdx.x * 128 + (jbeg >> 6)) * 128 + r;
  u64 mcur = mrow[0];

#pragma unroll 1
  for (int ph = 0; ph < nphase; ph += 2) {
    // re-stage s2 window every 32 phases (once when split>=8)
    if ((ph & 31) == 0) {
      __syncthreads();   // prior window's lss2 readers done
      if (tid < 256) *(f32x4*)(lss2 + tid * 4) =
        *(const f32x4*)(s2 + jbeg + (ph >> 5) * 1024 + tid * 4);
      __syncthreads();
    }
    // mask prefetch for next pair
    u64 mnx = (ph + 2 < nphase) ? mrow[((ph >> 1) + 1) * 128] : 0;
#pragma unroll
    for (int po = 0; po < 2; ++po) {
      const int p = ph + po;
      // ---- P-gen: 8 exps for (row r, j-window cpr*8 within this phase)
      const int pl = p & 31;
      f32x4 sA = *(const f32x4*)(lss2 + pl * 32 + cpr * 8);
      f32x4 sB = *(const f32x4*)(lss2 + pl * 32 + cpr * 8 + 4);
      const uint32_t by = (uint32_t)(mcur >> ((po * 4 + cpr) * 8)) & 0xffu;
      s16x8 P0;
#pragma unroll
      for (int e = 0; e < 4; ++e) {
        float x0 = s1r + sA[e];
        float pv0 = __expf(fmaxf(x0, LRALPHA * x0) - mi);
        pv0 = ((by >> e) & 1u) ? pv0 : 0.f;
        den += pv0; P0[e] = f2bf_fast(pv0);
        float x1 = s1r + sB[e];
        float pv1 = __expf(fmaxf(x1, LRALPHA * x1) - mi);
        pv1 = ((by >> (e + 4)) & 1u) ? pv1 : 0.f;
        den += pv1; P0[4 + e] = f2bf_fast(pv1);
      }
      *(s16x8*)(PL[p & 1] + (cpr * 128 + r) * 8) = P0;
      __syncthreads();   // P-tile ready (dbuf guards WAR with next producer)
      // ---- consume: B same-phase (transient regs), P from LDS, 16 MFMA
      const uint16_t* hB = HTf + ((size_t)((jbeg >> 5) + p) * 16 + cg * 4) * 512 + lane * 8;
      s16x8 Bv[4];
#pragma unroll
      for (int cb = 0; cb < 4; ++cb)
        Bv[cb] = *(const s16x8*)(hB + cb * 512);
      s16x8 F[4];
#pragma unroll
      for (int rt = 0; rt < 4; ++rt)
        F[rt] = *(const s16x8*)(PL[p & 1] + (q * 128 + rg * 64 + rt * 16 + m) * 8);
#pragma unroll
      for (int rt = 0; rt < 4; ++rt)
#pragma unroll
        for (int cb = 0; cb < 4; ++cb)
          acc[rt][cb] = __builtin_amdgcn_mfma_f32_16x16x32_bf16(F[rt], Bv[cb], acc[rt][cb], 0, 0, 0);
    }
    mcur = mnx;
  }

  // ---- denominator: 4 c-windows per row merged via LDS
  ldsden[cpr * 128 + r] = den;
  __syncthreads();
  if (tid < 128) {
    float d = ldsden[tid] + ldsden[128 + tid] + ldsden[256 + tid] + ldsden[384 + tid];
    pden[(size_t)sp * N_NODES + i0 + tid] = d;
  }
  // ---- pout: wave (rg,cg) tile 64x64
#pragma unroll
  for (int rt = 0; rt < 4; ++rt)
#pragma unroll
    for (int cb = 0; cb < 4; ++cb)
#pragma unroll
      for (int reg = 0; reg < 4; ++reg) {
        const int row = i0 + rg * 64 + rt * 16 + q * 4 + reg;
        const int col = cg * 64 + cb * 16 + m;
        pout[((size_t)sp * N_NODES + row) * FOUT + col] = acc[rt][cb][reg];
      }
}

// ---------------------------------------------------------------------------
// K3: out = elu( (sum_s pout[s]) / (sum_s pden[s]) ). In-place safe (split=1).
// ---------------------------------------------------------------------------
__global__ __launch_bounds__(256) void k_reduce(const float* __restrict__ pout,
                                                const float* __restrict__ pden,
                                                float* __restrict__ out,
                                                int split) {
  const int gid = blockIdx.x * 256 + threadIdx.x;
  const int i = gid >> 6;
  const int c = (gid & 63) << 2;
  f32x4 sum = {0.f,0.f,0.f,0.f};
  float den = 0.f;
  for (int s = 0; s < split; ++s) {
    sum += *(const f32x4*)(pout + ((size_t)s * N_NODES + i) * FOUT + c);
    den += pden[(size_t)s * N_NODES + i];
  }
  const float inv = 1.0f / den;
  f32x4 r;
#pragma unroll
  for (int e = 0; e < 4; ++e) {
    float v = sum[e] * inv;
    r[e] = v > 0.f ? v : (__expf(v) - 1.0f);
  }
  *(f32x4*)(out + (size_t)i * FOUT + c) = r;
}

// ---------------------------------------------------------------------------
extern "C" void kernel_launch(void* const* d_in, const int* in_sizes, int n_in,
                              void* d_out, int out_size, void* d_ws, size_t ws_size,
                              hipStream_t stream) {
  const float* X   = (const float*)d_in[0];   // [8192][512]
  const int*   adj = (const int*)d_in[1];     // [8192][8192]
  const float* W   = (const float*)d_in[2];   // [512][256]
  const float* a   = (const float*)d_in[3];   // [512]
  float* out = (float*)d_out;                 // [8192][256]

  char* ws = (char*)d_ws;
  uint16_t* HTf  = (uint16_t*)ws;                                   // 4 MB
  uint16_t* WThi = (uint16_t*)(ws + (4u << 20));                    // 256 KB
  uint16_t* WTlo = (uint16_t*)(ws + (4u << 20) + 262144);           // 256 KB
  float*    s1   = (float*)(ws + (4u << 20) + 524288);              // 32 KB
  float*    s2   = s1 + N_NODES;                                    // 32 KB
  float*    pden = s2 + N_NODES;                                    // <=256 KB
  u64*      M3   = (u64*)(ws + (6u << 20));                         // 8 MB
  const size_t pout_off = (size_t)16u << 20;
  const size_t slab = (size_t)N_NODES * FOUT * sizeof(float);       // 8 MB

  int split;
  if      (ws_size >= pout_off + 8 * slab) split = 8;
  else if (ws_size >= pout_off + 4 * slab) split = 4;
  else if (ws_size >= pout_off + 2 * slab) split = 2;
  else                                     split = 1;
  float* pout = (split == 1) ? out : (float*)(ws + pout_off);

  k_prep<<<dim3(512), dim3(256), 0, stream>>>(W, WThi, WTlo);
  k_pre<<<dim3(2560), dim3(256), 0, stream>>>(X, WThi, WTlo, a, adj, HTf, s1, s2, M3);
  k_attn<<<dim3(N_NODES / 128, split), dim3(512), 0, stream>>>(M3, HTf, s1, s2, pout, pden, split);
  k_reduce<<<dim3(N_NODES * FOUT / 4 / 256), dim3(256), 0, stream>>>(pout, pden, out, split);
}